// Round 3
// baseline (113.660 us; speedup 1.0000x reference)
//
#include <hip/hip_runtime.h>
#include <math.h>

// LFQ: D=20 bits, K=2^20, TEMP=0.005, x:[2,128,20] fp32, 256 tokens.
// Factorized softmax over the +-1 hypercube codebook:
//   p_t(k) = prod_j sigma(2 x_tj / T)^(b_kj) * sigma(-2 x_tj / T)^(1-b_kj)
// entropy_t = sum_j H(sigma(400 x_tj));  mean_probs = (1/256) Hi^T Lo with
// 10/10 bit split; mean_entro = -sum_k M_k log(M_k + 1e-10).
//
// R3: single fused kernel. 256 blocks (== CU count, all co-resident:
// ~41 KB LDS, 4 waves/CU, so capacity admits every block -> spin-sync is
// deadlock-free). Phase A: block b computes token b's P-bits, q, entropy,
// commit, Hi/Lo rows; publishes via release-store of a MAGIC flag (sentinel
// compare -> no flag-init kernel needed, works under 0xAA ws poison).
// Phase B: after acquiring all 256 flags (+agent fence to invalidate stale
// per-XCD L2 from prior replay), block b computes 64x64 tile (bx=b&15,
// by=b>>4) of M with double-buffered LDS, -m*logf epilogue, then a second
// flag rendezvous lets block 0 finalize the four scalars.

#define LFQ_D 20
#define NTOK 256
#define NQ (NTOK * LFQ_D)   // 5120
#define MAGIC 0x5AC0FFEEu

// ws layout (bytes):
//   Hi[t][a] float : 1 MB  @ 0
//   Lo[t][b] float : 1 MB  @ 1 MB
//   entPart[256] double    @ 2 MB
//   comPart[256] double    @ 2 MB + 2048
//   mePart [256] double    @ 2 MB + 4096
//   flagA  [256] uint      @ 2 MB + 6144
//   flagB  [256] uint      @ 2 MB + 7168

__global__ __launch_bounds__(256) void lfq_fused(
    const float* __restrict__ x, float* __restrict__ out,
    float* __restrict__ Hi, float* __restrict__ Lo,
    double* __restrict__ entPart, double* __restrict__ comPart,
    double* __restrict__ mePart,
    unsigned* __restrict__ flagA, unsigned* __restrict__ flagB) {
  const int blk = blockIdx.x;
  const int tid = threadIdx.x;

  __shared__ float P1[LFQ_D], P0[LFQ_D], hbuf[LFQ_D], cbuf[LFQ_D];

  // ---------------- Phase A: per-token (t = blk) ----------------
  {
    const int t = blk;
    if (tid < LFQ_D) {
      float xv = x[t * LFQ_D + tid];
      float z = 400.0f * xv;               // 2x/TEMP
      float az = fabsf(z);
      float e = expf(-az);                 // underflows to 0 for big |z|
      float s = e / (1.0f + e);            // sigma(-|z|)
      float p1 = (z >= 0.0f) ? (1.0f - s) : s;  // P(bit=+1)
      P1[tid] = p1;
      P0[tid] = 1.0f - p1;
      // stable binary entropy (nats): H = log1p(e) + |z| * sigma(-|z|)
      hbuf[tid] = log1pf(e) + az * s;
      float qv = (xv > 0.0f) ? 1.0f : -1.0f;
      out[t * LFQ_D + tid] = qv;           // straight-through forward value
      float dx = xv - qv;
      cbuf[tid] = dx * dx;
    }
    __syncthreads();
    if (tid == 0) {
      float hs = 0.0f, cs = 0.0f;
      for (int j = 0; j < LFQ_D; ++j) { hs += hbuf[j]; cs += cbuf[j]; }
      entPart[t] = (double)hs;
      comPart[t] = (double)cs;
    }
    // Hi over high 10 bits (cols j=0..9): bit_j = (a >> (9-j)) & 1
#pragma unroll
    for (int r = 0; r < 4; ++r) {
      int a = tid + r * 256;
      float prod = 1.0f;
#pragma unroll
      for (int j = 0; j < 10; ++j) {
        int bit = (a >> (9 - j)) & 1;
        prod *= bit ? P1[j] : P0[j];
      }
      Hi[t * 1024 + a] = prod;
    }
    // Lo over low 10 bits (cols j=10..19)
#pragma unroll
    for (int r = 0; r < 4; ++r) {
      int a = tid + r * 256;
      float prod = 1.0f;
#pragma unroll
      for (int m = 0; m < 10; ++m) {
        int bit = (a >> (9 - m)) & 1;
        prod *= bit ? P1[10 + m] : P0[10 + m];
      }
      Lo[t * 1024 + a] = prod;
    }
    __threadfence();   // each thread's global writes device-visible
    __syncthreads();
    if (tid == 0)
      __hip_atomic_store(&flagA[t], MAGIC, __ATOMIC_RELEASE,
                         __HIP_MEMORY_SCOPE_AGENT);
  }

  // ---------------- rendezvous: wait for all 256 tokens ----------------
  {
    bool rdy = false;
    do {
      unsigned v = __hip_atomic_load(&flagA[tid], __ATOMIC_RELAXED,
                                     __HIP_MEMORY_SCOPE_AGENT);
      rdy = (v == MAGIC);
    } while (__syncthreads_and((int)rdy) == 0);
    __threadfence();   // acquire: invalidate stale L1/L2 before reading Hi/Lo
  }

  // ---------------- Phase B: 64x64 tile of M, entropy epilogue ----------
  __shared__ float sHi[2][32][64];
  __shared__ float sLo[2][32][64];
  const int tx = tid & 15, ty = tid >> 4;
  const int a0 = (blk & 15) * 64, b0 = (blk >> 4) * 64;

  const int r0 = tid >> 4;            // rows 0..15
  const int r1 = r0 + 16;             // rows 16..31
  const int c0 = (tid & 15) * 4;      // col 0..60 step 4

  float4 h0 = *(const float4*)&Hi[(0 * 32 + r0) * 1024 + a0 + c0];
  float4 h1 = *(const float4*)&Hi[(0 * 32 + r1) * 1024 + a0 + c0];
  float4 l0 = *(const float4*)&Lo[(0 * 32 + r0) * 1024 + b0 + c0];
  float4 l1 = *(const float4*)&Lo[(0 * 32 + r1) * 1024 + b0 + c0];
  *(float4*)&sHi[0][r0][c0] = h0;
  *(float4*)&sHi[0][r1][c0] = h1;
  *(float4*)&sLo[0][r0][c0] = l0;
  *(float4*)&sLo[0][r1][c0] = l1;
  __syncthreads();

  float acc[4][4];
#pragma unroll
  for (int i = 0; i < 4; ++i)
#pragma unroll
    for (int j = 0; j < 4; ++j) acc[i][j] = 0.0f;

  for (int c = 0; c < 8; ++c) {
    const int cur = c & 1, nxt = cur ^ 1;
    if (c < 7) {  // issue next chunk's global loads before compute
      h0 = *(const float4*)&Hi[((c + 1) * 32 + r0) * 1024 + a0 + c0];
      h1 = *(const float4*)&Hi[((c + 1) * 32 + r1) * 1024 + a0 + c0];
      l0 = *(const float4*)&Lo[((c + 1) * 32 + r0) * 1024 + b0 + c0];
      l1 = *(const float4*)&Lo[((c + 1) * 32 + r1) * 1024 + b0 + c0];
    }
#pragma unroll
    for (int tt = 0; tt < 32; ++tt) {
      float4 ha = *(const float4*)&sHi[cur][tt][tx * 4];
      float4 lb = *(const float4*)&sLo[cur][tt][ty * 4];
      float hav[4] = {ha.x, ha.y, ha.z, ha.w};
      float lbv[4] = {lb.x, lb.y, lb.z, lb.w};
#pragma unroll
      for (int i = 0; i < 4; ++i)
#pragma unroll
        for (int j = 0; j < 4; ++j)
          acc[i][j] = fmaf(hav[i], lbv[j], acc[i][j]);
    }
    if (c < 7) {
      *(float4*)&sHi[nxt][r0][c0] = h0;
      *(float4*)&sHi[nxt][r1][c0] = h1;
      *(float4*)&sLo[nxt][r0][c0] = l0;
      *(float4*)&sLo[nxt][r1][c0] = l1;
    }
    __syncthreads();
  }

  // epilogue: -m*log(m+1e-10) with HW v_log_f32
  float tsum = 0.0f;
#pragma unroll
  for (int i = 0; i < 4; ++i)
#pragma unroll
    for (int j = 0; j < 4; ++j) {
      float m = acc[i][j] * (1.0f / 256.0f);
      tsum -= m * __logf(m + 1e-10f);
    }
  __shared__ double red[256];
  red[tid] = (double)tsum;
  __syncthreads();
  for (int s = 128; s > 0; s >>= 1) {
    if (tid < s) red[tid] += red[tid + s];
    __syncthreads();
  }
  if (tid == 0) {
    mePart[blk] = red[0];
    __threadfence();
    __hip_atomic_store(&flagB[blk], MAGIC, __ATOMIC_RELEASE,
                       __HIP_MEMORY_SCOPE_AGENT);
  }

  // ---------------- finalize: block 0 only ----------------
  if (blk == 0) {
    bool rdy = false;
    do {
      unsigned v = __hip_atomic_load(&flagB[tid], __ATOMIC_RELAXED,
                                     __HIP_MEMORY_SCOPE_AGENT);
      rdy = (v == MAGIC);
    } while (__syncthreads_and((int)rdy) == 0);
    __threadfence();

    __shared__ double r1[256], r2[256], r3[256];
    r1[tid] = entPart[tid];
    r2[tid] = comPart[tid];
    r3[tid] = mePart[tid];
    __syncthreads();
    for (int s = 128; s > 0; s >>= 1) {
      if (tid < s) {
        r1[tid] += r1[tid + s];
        r2[tid] += r2[tid + s];
        r3[tid] += r3[tid + s];
      }
      __syncthreads();
    }
    if (tid == 0) {
      double entro_mean_s = r1[0] / 256.0;
      double commit = r2[0] / (double)NQ;
      double me = r3[0];
      out[NQ + 0] = (float)entro_mean_s;
      out[NQ + 1] = (float)me;
      out[NQ + 2] = (float)(entro_mean_s - me);  // ALPHA=1
      out[NQ + 3] = (float)commit;
    }
  }
}

extern "C" void kernel_launch(void* const* d_in, const int* in_sizes, int n_in,
                              void* d_out, int out_size, void* d_ws, size_t ws_size,
                              hipStream_t stream) {
  const float* x = (const float*)d_in[0];
  float* out = (float*)d_out;
  char* ws = (char*)d_ws;
  float* Hi = (float*)(ws);
  float* Lo = (float*)(ws + (1u << 20));
  double* entPart = (double*)(ws + (2u << 20));
  double* comPart = (double*)(ws + (2u << 20) + 2048);
  double* mePart  = (double*)(ws + (2u << 20) + 4096);
  unsigned* flagA = (unsigned*)(ws + (2u << 20) + 6144);
  unsigned* flagB = (unsigned*)(ws + (2u << 20) + 7168);

  lfq_fused<<<NTOK, 256, 0, stream>>>(x, out, Hi, Lo, entPart, comPart,
                                      mePart, flagA, flagB);
}

// Round 4
// 64.569 us; speedup vs baseline: 1.7603x; 1.7603x over previous
//
#include <hip/hip_runtime.h>
#include <math.h>

// LFQ: D=20 bits, K=2^20, TEMP=0.005, x:[2,128,20] fp32, 256 tokens.
// Factorized softmax over the +-1 hypercube codebook:
//   p_t(k) = prod_j sigma(2 x_tj / T)^(b_kj) * sigma(-2 x_tj / T)^(1-b_kj)
// entropy_t = sum_j H(sigma(400 x_tj)); mean_probs M = (1/256) Hi^T Lo
// (10/10 bit split); mean_entro = -sum_k M_k log(M_k + 1e-10).
//
// R4: ONE kernel, 256 blocks, NO inter-block rendezvous for the GEMM.
// Block (bx=blk&15, by=blk>>4) owns tile M[a0:a0+64][b0:b0+64]; its a/b high
// 4 bits are fixed, so Hi[a0+r][t] = C[t]*VAH[r>>3][t]*VAL[r&7][t] with tiny
// 8x256 tables -> each block recomputes its own bf16 panels from x in LDS
// (zero global Hi/Lo traffic, no flags). Tile GEMM via mfma_f32_16x16x32_bf16
// (bf16 exact for the dominant 0/1-valued entries; soft-bit rounding ~2^-9).
// Final scalars: R2-proven atomic-counter last-block finalize (ws poison
// 0xAA..AA used as the counter's known start value; NO spin barrier -- R3
// showed a full 256-block spin rendezvous costs ~60us).

#define RS 264    // panel row stride (ushorts); 528B = 16B-mult, bank-friendly
#define VTS 260   // V-table row stride (floats); 1040B, 16B-mult, banks 4g
#define POISON 0xAAAAAAAAu

typedef float f32x4 __attribute__((ext_vector_type(4)));
typedef short bf16x8 __attribute__((ext_vector_type(8)));

__device__ inline unsigned pk_bf16x2(float a, float b) {  // RNE f32->bf16 pair
  unsigned ua = __float_as_uint(a); ua += 0x7FFFu + ((ua >> 16) & 1u);
  unsigned ub = __float_as_uint(b); ub += 0x7FFFu + ((ub >> 16) & 1u);
  return (ua >> 16) | (ub & 0xFFFF0000u);
}

__global__ __launch_bounds__(256) void lfq_one(
    const float* __restrict__ x, float* __restrict__ out,
    double* __restrict__ entPart, double* __restrict__ comPart,
    double* __restrict__ mePart, unsigned* __restrict__ counter) {
  const int blk = blockIdx.x;
  const int tid = threadIdx.x;

  __shared__ float sP1[20][256];                       // 20 KB
  __shared__ float sVAH[8][VTS], sVAL[8][VTS];         // A-tables (C folded in)
  __shared__ float sVBH[8][VTS], sVBL[8][VTS];         // 4*8.3 KB
  __shared__ unsigned short sA[64 * RS];               // 33 KB bf16 panel
  __shared__ unsigned short sB[64 * RS];               // 33 KB
  __shared__ double red[256];                          // 2 KB
  __shared__ float hb[20], cb[20];
  __shared__ int lastBlk;

  // ---- phase 1: sigmoid table P1[j][t] (thread t = tid), token-blk scalars
  {
    const int t = tid;
    float xv[20];
    const float4* xp = (const float4*)(x + t * 20);    // 80B rows: 16B aligned
#pragma unroll
    for (int k = 0; k < 5; ++k) {
      float4 v = xp[k];
      xv[4 * k + 0] = v.x; xv[4 * k + 1] = v.y;
      xv[4 * k + 2] = v.z; xv[4 * k + 3] = v.w;
    }
#pragma unroll
    for (int j = 0; j < 20; ++j) {
      float z = 400.f * xv[j];                         // 2x/TEMP
      float az = fabsf(z);
      float e = __expf(-az);
      float s = e / (1.f + e);                         // sigma(-|z|)
      sP1[j][t] = (z >= 0.f) ? (1.f - s) : s;          // P(bit=+1)
    }
  }
  if (tid < 20) {  // this block's token: q, entropy, commit terms
    float xv = x[blk * 20 + tid];
    float z = 400.f * xv, az = fabsf(z);
    float e = __expf(-az), s = e / (1.f + e);
    hb[tid] = log1pf(e) + az * s;                      // stable binary entropy
    float qv = (xv > 0.f) ? 1.f : -1.f;
    out[blk * 20 + tid] = qv;
    float dx = xv - qv;
    cb[tid] = dx * dx;
  }
  __syncthreads();
  if (tid == 0) {
    float hs = 0.f, cs = 0.f;
#pragma unroll
    for (int j = 0; j < 20; ++j) { hs += hb[j]; cs += cb[j]; }
    entPart[blk] = (double)hs;
    comPart[blk] = (double)cs;
  }

  // ---- phase 2: per-t tables. a bits 9..6 fixed by bx, 5..0 = r; Lo likewise.
  {
    const int t = tid;
    const int ahi = blk & 15, bhi = blk >> 4;
    float c = 1.f;
#pragma unroll
    for (int j = 0; j < 4; ++j) {                      // j=0..3 <-> a bits 9..6
      float p = sP1[j][t];
      c *= ((ahi >> (3 - j)) & 1) ? p : (1.f - p);
    }
#pragma unroll
    for (int j = 0; j < 4; ++j) {                      // j=10..13 <-> b bits 9..6
      float p = sP1[10 + j][t];
      c *= ((bhi >> (3 - j)) & 1) ? p : (1.f - p);
    }
    float p4 = sP1[4][t], p5 = sP1[5][t], p6 = sP1[6][t];
    float p7 = sP1[7][t], p8 = sP1[8][t], p9 = sP1[9][t];
    float pe = sP1[14][t], pf = sP1[15][t], pg = sP1[16][t];
    float ph = sP1[17][t], pi = sP1[18][t], pj = sP1[19][t];
#pragma unroll
    for (int g = 0; g < 8; ++g) {
      sVAH[g][t] = c * ((g & 4) ? p4 : 1.f - p4) * ((g & 2) ? p5 : 1.f - p5)
                     * ((g & 1) ? p6 : 1.f - p6);      // j=4..6 <-> r bits 5..3
      sVAL[g][t] =     ((g & 4) ? p7 : 1.f - p7) * ((g & 2) ? p8 : 1.f - p8)
                     * ((g & 1) ? p9 : 1.f - p9);      // j=7..9 <-> r bits 2..0
      sVBH[g][t] =     ((g & 4) ? pe : 1.f - pe) * ((g & 2) ? pf : 1.f - pf)
                     * ((g & 1) ? pg : 1.f - pg);      // j=14..16 <-> s bits 5..3
      sVBL[g][t] =     ((g & 4) ? ph : 1.f - ph) * ((g & 2) ? pi : 1.f - pi)
                     * ((g & 1) ? pj : 1.f - pj);      // j=17..19 <-> s bits 2..0
    }
  }
  __syncthreads();

  // ---- phase 3: bf16 panels A[r][t]=VAH*VAL (C folded), B[s][t]=VBH*VBL
  {
    const int r = tid & 63, tc = tid >> 6;
    const int gH = r >> 3, gL = r & 7;
    unsigned short* arow = sA + r * RS;
    unsigned short* brow = sB + r * RS;
#pragma unroll
    for (int it = 0; it < 16; ++it) {
      int t = tc * 64 + it * 4;
      float4 h = *(const float4*)&sVAH[gH][t];
      float4 l = *(const float4*)&sVAL[gL][t];
      unsigned lo = pk_bf16x2(h.x * l.x, h.y * l.y);
      unsigned hi = pk_bf16x2(h.z * l.z, h.w * l.w);
      *(uint2*)(arow + t) = make_uint2(lo, hi);
      float4 h2 = *(const float4*)&sVBH[gH][t];
      float4 l2 = *(const float4*)&sVBL[gL][t];
      unsigned lo2 = pk_bf16x2(h2.x * l2.x, h2.y * l2.y);
      unsigned hi2 = pk_bf16x2(h2.z * l2.z, h2.w * l2.w);
      *(uint2*)(brow + t) = make_uint2(lo2, hi2);
    }
  }
  __syncthreads();

  // ---- phase 4: tile GEMM. wave w: rows w*16+(lane&15); 4 col-tiles.
  // A-frag: A[m=lane&15][k=quad*8+j]; B-frag: B[k=quad*8+j][n=lane&15];
  // both read t-contiguous 16B from the [row][t] panels. C/D layout is
  // irrelevant: the epilogue is a pure reduction over all acc elements.
  const int lane = tid & 63, w = tid >> 6;
  const int m16 = lane & 15, q = lane >> 4;
  f32x4 acc[4];
#pragma unroll
  for (int ct = 0; ct < 4; ++ct) acc[ct] = (f32x4){0.f, 0.f, 0.f, 0.f};
  const unsigned short* ap = sA + (w * 16 + m16) * RS + q * 8;
  const unsigned short* bp = sB + m16 * RS + q * 8;
#pragma unroll
  for (int ks = 0; ks < 8; ++ks) {
    bf16x8 af = *(const bf16x8*)(ap + ks * 32);
    bf16x8 b0 = *(const bf16x8*)(bp + ks * 32);
    bf16x8 b1 = *(const bf16x8*)(bp + 16 * RS + ks * 32);
    bf16x8 b2 = *(const bf16x8*)(bp + 32 * RS + ks * 32);
    bf16x8 b3 = *(const bf16x8*)(bp + 48 * RS + ks * 32);
    acc[0] = __builtin_amdgcn_mfma_f32_16x16x32_bf16(af, b0, acc[0], 0, 0, 0);
    acc[1] = __builtin_amdgcn_mfma_f32_16x16x32_bf16(af, b1, acc[1], 0, 0, 0);
    acc[2] = __builtin_amdgcn_mfma_f32_16x16x32_bf16(af, b2, acc[2], 0, 0, 0);
    acc[3] = __builtin_amdgcn_mfma_f32_16x16x32_bf16(af, b3, acc[3], 0, 0, 0);
  }

  // ---- phase 5: -m*log(m+1e-10) epilogue + block reduce
  float ts = 0.f;
#pragma unroll
  for (int ct = 0; ct < 4; ++ct)
#pragma unroll
    for (int i = 0; i < 4; ++i) {
      float m = acc[ct][i] * (1.f / 256.f);
      ts -= m * __logf(m + 1e-10f);
    }
  red[tid] = (double)ts;
  __syncthreads();
  for (int s = 128; s > 0; s >>= 1) {
    if (tid < s) red[tid] += red[tid + s];
    __syncthreads();
  }
  if (tid == 0) {
    mePart[blk] = red[0];
    __threadfence();                       // release this block's partials
    unsigned old = atomicAdd(counter, 1u); // ws poison = known start value
    lastBlk = ((old - POISON) == 255u) ? 1 : 0;
  }
  __syncthreads();

  // ---- finalize: last-arriving block only (R2-proven pattern, no spin)
  if (lastBlk) {
    __threadfence();                       // acquire all blocks' partials
    __shared__ double r1[256], r2[256], r3[256];
    r1[tid] = entPart[tid];
    r2[tid] = comPart[tid];
    r3[tid] = mePart[tid];
    __syncthreads();
    for (int s = 128; s > 0; s >>= 1) {
      if (tid < s) {
        r1[tid] += r1[tid + s];
        r2[tid] += r2[tid + s];
        r3[tid] += r3[tid + s];
      }
      __syncthreads();
    }
    if (tid == 0) {
      double em = r1[0] / 256.0;           // entro_mean_s
      double cm = r2[0] / 5120.0;          // commit_loss
      double me = r3[0];                   // mean_entro
      out[5120] = (float)em;
      out[5121] = (float)me;
      out[5122] = (float)(em - me);        // entro_loss (ALPHA=1)
      out[5123] = (float)cm;
    }
  }
}

extern "C" void kernel_launch(void* const* d_in, const int* in_sizes, int n_in,
                              void* d_out, int out_size, void* d_ws, size_t ws_size,
                              hipStream_t stream) {
  const float* x = (const float*)d_in[0];
  float* out = (float*)d_out;
  char* ws = (char*)d_ws;
  double* entPart = (double*)(ws);
  double* comPart = (double*)(ws + 2048);
  double* mePart  = (double*)(ws + 4096);
  unsigned* counter = (unsigned*)(ws + 6144);

  lfq_one<<<256, 256, 0, stream>>>(x, out, entPart, comPart, mePart, counter);
}

// Round 5
// 63.094 us; speedup vs baseline: 1.8014x; 1.0234x over previous
//
#include <hip/hip_runtime.h>
#include <math.h>

// LFQ: D=20 bits, K=2^20, TEMP=0.005, x:[2,128,20] fp32, 256 tokens.
// Factorized softmax over the +-1 hypercube codebook:
//   p_t(k) = prod_j sigma(2 x_tj / T)^(b_kj) * sigma(-2 x_tj / T)^(1-b_kj)
// entropy_t = sum_j H(sigma(400 x_tj)); mean_probs M = (1/256) Hi^T Lo
// (10/10 bit split); mean_entro = -sum_k M_k log(M_k + 1e-10).
//
// R5: 256 blocks x 512 threads (8 waves = 2 waves/SIMD; R4's 1 wave/SIMD
// exposed all VALU/LDS latency -> ~17us kernel). Thread tid: side=tid>>8
// (A or B panel), t=tid&255 (token column). Each thread computes its 10
// sigmoids + tables in REGISTERS and writes its 64 bf16 panel values
// directly with wave-contiguous ds_write_b16 (no sP1 / V-table LDS arrays,
// no transpose round-trip; LDS 131KB -> 78KB). Tile GEMM: wave w -> rows
// (w&3)*16, cols (w>>2)*32, 2 accs, mfma_f32_16x16x32_bf16. Scalars via
// R2/R4-proven atomic-counter last-block finalize (ws poison = counter
// start; no spin barrier -- R3 showed that costs ~60us).

#define RS 264    // panel row stride in ushorts: 528B rows; frag reads and
                  // column writes are both 8-lane-phase bank-conflict-free
#define POISON 0xAAAAAAAAu

typedef float f32x4 __attribute__((ext_vector_type(4)));
typedef short bf16x8 __attribute__((ext_vector_type(8)));

__device__ inline unsigned short pk_bf16(float a) {  // RNE f32->bf16
  unsigned ua = __float_as_uint(a);
  ua += 0x7FFFu + ((ua >> 16) & 1u);
  return (unsigned short)(ua >> 16);
}

__global__ __launch_bounds__(512) void lfq_one(
    const float* __restrict__ x, float* __restrict__ out,
    double* __restrict__ entPart, double* __restrict__ comPart,
    double* __restrict__ mePart, unsigned* __restrict__ counter) {
  const int blk = blockIdx.x;
  const int tid = threadIdx.x;

  __shared__ unsigned short sP[128 * RS];   // A = rows 0..63, B = rows 64..127
  __shared__ double red[512];
  __shared__ float hb[20], cb[20];
  __shared__ int lastBlk;

  // ---- phase 1: token-blk scalars (entropy/commit/q) ----
  if (tid < 20) {
    float xv = x[blk * 20 + tid];
    float z = 400.f * xv, az = fabsf(z);
    float e = __expf(-az), s = e / (1.f + e);
    hb[tid] = log1pf(e) + az * s;            // stable binary entropy (nats)
    float qv = (xv > 0.f) ? 1.f : -1.f;
    out[blk * 20 + tid] = qv;
    float dx = xv - qv;
    cb[tid] = dx * dx;
  }

  // ---- phase 2: build this side's panel column t, all in registers ----
  {
    const int side = tid >> 8;               // 0: A-panel, 1: B-panel
    const int t = tid & 255;
    const int jo = side * 10;                // x-column offset for this side
    const int hi4 = side ? (blk >> 4) : (blk & 15);  // tile's fixed 4 bits

    // 10 sigmoids p[j] = P(bit_j = +1), j = jo..jo+9 (float2 loads: 8B align)
    float p[10];
    const float2* xp = (const float2*)(x + t * 20 + jo);
#pragma unroll
    for (int k = 0; k < 5; ++k) {
      float2 v = xp[k];
      float zz0 = 400.f * v.x, zz1 = 400.f * v.y;
      float a0 = fabsf(zz0), a1 = fabsf(zz1);
      float e0 = __expf(-a0), e1 = __expf(-a1);
      float s0 = e0 / (1.f + e0), s1 = e1 / (1.f + e1);
      p[2 * k]     = (zz0 >= 0.f) ? (1.f - s0) : s0;
      p[2 * k + 1] = (zz1 >= 0.f) ? (1.f - s1) : s1;
    }
    // fold tile's fixed high bits (j = 0..3 of this side) into c
    float c = 1.f;
#pragma unroll
    for (int j = 0; j < 4; ++j)
      c *= ((hi4 >> (3 - j)) & 1) ? p[j] : (1.f - p[j]);
    // tables over row bits: gH <-> j=4,5,6 (c folded), gL <-> j=7,8,9
    float cvh[8], vl[8];
#pragma unroll
    for (int g = 0; g < 8; ++g) {
      cvh[g] = c * ((g & 4) ? p[4] : 1.f - p[4])
                 * ((g & 2) ? p[5] : 1.f - p[5])
                 * ((g & 1) ? p[6] : 1.f - p[6]);
      vl[g]  =     ((g & 4) ? p[7] : 1.f - p[7])
                 * ((g & 2) ? p[8] : 1.f - p[8])
                 * ((g & 1) ? p[9] : 1.f - p[9]);
    }
    // 64 products -> bf16 -> contiguous column writes (conflict-free)
    unsigned short* panel = sP + side * 64 * RS;
#pragma unroll
    for (int r = 0; r < 64; ++r)
      panel[r * RS + t] = pk_bf16(cvh[r >> 3] * vl[r & 7]);
  }
  __syncthreads();

  if (tid == 0) {  // after barrier: hb/cb visible
    float hs = 0.f, cs = 0.f;
#pragma unroll
    for (int j = 0; j < 20; ++j) { hs += hb[j]; cs += cb[j]; }
    entPart[blk] = (double)hs;
    comPart[blk] = (double)cs;
  }

  // ---- phase 3: tile GEMM. wave w: rows (w&3)*16, cols (w>>2)*32 ----
  // A-frag lane: A[m=lane&15][k=q*8+j]; B-frag lane: B[k][n=lane&15];
  // both are t-contiguous 16B reads from the [row][t] panels. C/D layout
  // irrelevant: epilogue reduces over all acc elements.
  const int lane = tid & 63, w = tid >> 6;
  const int m16 = lane & 15, q = lane >> 4;
  const unsigned short* ap = sP + ((w & 3) * 16 + m16) * RS + q * 8;
  const unsigned short* bp = sP + (64 + (w >> 2) * 32 + m16) * RS + q * 8;
  f32x4 acc0 = {0.f, 0.f, 0.f, 0.f}, acc1 = {0.f, 0.f, 0.f, 0.f};
#pragma unroll
  for (int ks = 0; ks < 8; ++ks) {
    bf16x8 af = *(const bf16x8*)(ap + ks * 32);
    bf16x8 b0 = *(const bf16x8*)(bp + ks * 32);
    bf16x8 b1 = *(const bf16x8*)(bp + 16 * RS + ks * 32);
    acc0 = __builtin_amdgcn_mfma_f32_16x16x32_bf16(af, b0, acc0, 0, 0, 0);
    acc1 = __builtin_amdgcn_mfma_f32_16x16x32_bf16(af, b1, acc1, 0, 0, 0);
  }

  // ---- phase 4: -m*log(m+1e-10) epilogue + block reduce ----
  float ts = 0.f;
#pragma unroll
  for (int i = 0; i < 4; ++i) {
    float m0 = acc0[i] * (1.f / 256.f);
    ts -= m0 * __logf(m0 + 1e-10f);
    float m1 = acc1[i] * (1.f / 256.f);
    ts -= m1 * __logf(m1 + 1e-10f);
  }
  red[tid] = (double)ts;
  __syncthreads();
  for (int s = 256; s > 0; s >>= 1) {
    if (tid < s) red[tid] += red[tid + s];
    __syncthreads();
  }
  if (tid == 0) {
    mePart[blk] = red[0];
    __threadfence();                       // release this block's partials
    unsigned old = atomicAdd(counter, 1u); // ws poison = known start value
    lastBlk = ((old - POISON) == 255u) ? 1 : 0;
  }
  __syncthreads();

  // ---- finalize: last-arriving block only ----
  if (lastBlk) {
    __threadfence();                       // acquire all blocks' partials
    __shared__ double r1[256], r2[256], r3[256];
    if (tid < 256) {
      r1[tid] = entPart[tid];
      r2[tid] = comPart[tid];
      r3[tid] = mePart[tid];
    }
    __syncthreads();
    for (int s = 128; s > 0; s >>= 1) {
      if (tid < s) {
        r1[tid] += r1[tid + s];
        r2[tid] += r2[tid + s];
        r3[tid] += r3[tid + s];
      }
      __syncthreads();
    }
    if (tid == 0) {
      double em = r1[0] / 256.0;           // entro_mean_s
      double cm = r2[0] / 5120.0;          // commit_loss
      double me = r3[0];                   // mean_entro
      out[5120] = (float)em;
      out[5121] = (float)me;
      out[5122] = (float)(em - me);        // entro_loss (ALPHA=1)
      out[5123] = (float)cm;
    }
  }
}

extern "C" void kernel_launch(void* const* d_in, const int* in_sizes, int n_in,
                              void* d_out, int out_size, void* d_ws, size_t ws_size,
                              hipStream_t stream) {
  const float* x = (const float*)d_in[0];
  float* out = (float*)d_out;
  char* ws = (char*)d_ws;
  double* entPart = (double*)(ws);
  double* comPart = (double*)(ws + 2048);
  double* mePart  = (double*)(ws + 4096);
  unsigned* counter = (unsigned*)(ws + 6144);

  lfq_one<<<256, 512, 0, stream>>>(x, out, entPart, comPart, mePart, counter);
}

// Round 6
// 62.933 us; speedup vs baseline: 1.8060x; 1.0025x over previous
//
#include <hip/hip_runtime.h>
#include <math.h>

// LFQ: D=20 bits, K=2^20, TEMP=0.005, x:[2,128,20] fp32, 256 tokens.
// Factorized softmax over the +-1 hypercube codebook:
//   p_t(k) = prod_j sigma(2 x_tj / T)^(b_kj) * sigma(-2 x_tj / T)^(1-b_kj)
// entropy_t = sum_j H(sigma(400 x_tj)); mean_probs M = (1/256) Hi^T Lo
// (10/10 bit split); mean_entro = -sum_k M_k log(M_k + 1e-10).
//
// R6: R5 structure (256 blocks x 512 thr, register panel build, bf16 MFMA
// tile GEMM) with the inter-block tail rebuilt:
//  - HIERARCHICAL atomic counter (16 level-1 counters spaced 128B + 1
//    level-2): R4/R5's single counter took ~255 serialized same-line
//    cross-XCD RMWs (~10us, the unexplained kernel cost). Now <=16 per line.
//  - all block partials are plain float stores (no contention), reductions
//    via wave shuffles; barrier count ~20 -> ~5.
//  - poison sentinel (ws = 0xAA..) still used as counters' start value.

#define RS 264    // panel row stride in ushorts: 528B rows; frag reads and
                  // column writes both bank-phase conflict-free
#define POISON 0xAAAAAAAAu

typedef float f32x4 __attribute__((ext_vector_type(4)));
typedef short bf16x8 __attribute__((ext_vector_type(8)));

__device__ inline unsigned short pk_bf16(float a) {  // RNE f32->bf16
  unsigned ua = __float_as_uint(a);
  ua += 0x7FFFu + ((ua >> 16) & 1u);
  return (unsigned short)(ua >> 16);
}

__global__ __launch_bounds__(512) void lfq_one(
    const float* __restrict__ x, float* __restrict__ out,
    float* __restrict__ entP, float* __restrict__ comP,
    float* __restrict__ meP, unsigned* __restrict__ cnt1,
    unsigned* __restrict__ cnt2) {
  const int blk = blockIdx.x;
  const int tid = threadIdx.x;
  const int lane = tid & 63, w = tid >> 6;

  __shared__ unsigned short sP[128 * RS];   // A rows 0..63, B rows 64..127
  __shared__ float wpart[8];
  __shared__ float fe[8], fc[8], fm[8];
  __shared__ int lastBlk;

  // ---- phase 1: this block's token scalars (wave 0 only, shuffle-reduced)
  if (tid < 64) {
    float h = 0.f, cterm = 0.f;
    if (tid < 20) {
      float xv = x[blk * 20 + tid];
      float z = 400.f * xv, az = fabsf(z);
      float e = __expf(-az), s = e / (1.f + e);
      h = log1pf(e) + az * s;               // stable binary entropy (nats)
      float qv = (xv > 0.f) ? 1.f : -1.f;
      out[blk * 20 + tid] = qv;             // straight-through forward value
      float dx = xv - qv;
      cterm = dx * dx;
    }
#pragma unroll
    for (int off = 32; off > 0; off >>= 1) {
      h += __shfl_down(h, off, 64);
      cterm += __shfl_down(cterm, off, 64);
    }
    if (tid == 0) { entP[blk] = h; comP[blk] = cterm; }  // plain stores
  }

  // ---- phase 2: build this side's panel column t, all in registers ----
  {
    const int side = tid >> 8;               // 0: A-panel, 1: B-panel
    const int t = tid & 255;
    const int jo = side * 10;                // x-column offset for this side
    const int hi4 = side ? (blk >> 4) : (blk & 15);  // tile's fixed 4 bits

    float p[10];
    const float2* xp = (const float2*)(x + t * 20 + jo);
#pragma unroll
    for (int k = 0; k < 5; ++k) {
      float2 v = xp[k];
      float zz0 = 400.f * v.x, zz1 = 400.f * v.y;
      float a0 = fabsf(zz0), a1 = fabsf(zz1);
      float e0 = __expf(-a0), e1 = __expf(-a1);
      float s0 = e0 / (1.f + e0), s1 = e1 / (1.f + e1);
      p[2 * k]     = (zz0 >= 0.f) ? (1.f - s0) : s0;
      p[2 * k + 1] = (zz1 >= 0.f) ? (1.f - s1) : s1;
    }
    float c = 1.f;
#pragma unroll
    for (int j = 0; j < 4; ++j)
      c *= ((hi4 >> (3 - j)) & 1) ? p[j] : (1.f - p[j]);
    float cvh[8], vl[8];
#pragma unroll
    for (int g = 0; g < 8; ++g) {
      cvh[g] = c * ((g & 4) ? p[4] : 1.f - p[4])
                 * ((g & 2) ? p[5] : 1.f - p[5])
                 * ((g & 1) ? p[6] : 1.f - p[6]);
      vl[g]  =     ((g & 4) ? p[7] : 1.f - p[7])
                 * ((g & 2) ? p[8] : 1.f - p[8])
                 * ((g & 1) ? p[9] : 1.f - p[9]);
    }
    unsigned short* panel = sP + side * 64 * RS;
#pragma unroll
    for (int r = 0; r < 64; ++r)
      panel[r * RS + t] = pk_bf16(cvh[r >> 3] * vl[r & 7]);
  }
  __syncthreads();

  // ---- phase 3: tile GEMM. wave w: rows (w&3)*16, cols (w>>2)*32 ----
  const int m16 = lane & 15, q = lane >> 4;
  const unsigned short* ap = sP + ((w & 3) * 16 + m16) * RS + q * 8;
  const unsigned short* bp = sP + (64 + (w >> 2) * 32 + m16) * RS + q * 8;
  f32x4 acc0 = {0.f, 0.f, 0.f, 0.f}, acc1 = {0.f, 0.f, 0.f, 0.f};
#pragma unroll
  for (int ks = 0; ks < 8; ++ks) {
    bf16x8 af = *(const bf16x8*)(ap + ks * 32);
    bf16x8 b0 = *(const bf16x8*)(bp + ks * 32);
    bf16x8 b1 = *(const bf16x8*)(bp + 16 * RS + ks * 32);
    acc0 = __builtin_amdgcn_mfma_f32_16x16x32_bf16(af, b0, acc0, 0, 0, 0);
    acc1 = __builtin_amdgcn_mfma_f32_16x16x32_bf16(af, b1, acc1, 0, 0, 0);
  }

  // ---- phase 4: -m*log(m+1e-10) epilogue, shuffle reduce ----
  float ts = 0.f;
#pragma unroll
  for (int i = 0; i < 4; ++i) {
    float m0 = acc0[i] * (1.f / 256.f);
    ts -= m0 * __logf(m0 + 1e-10f);
    float m1 = acc1[i] * (1.f / 256.f);
    ts -= m1 * __logf(m1 + 1e-10f);
  }
#pragma unroll
  for (int off = 32; off > 0; off >>= 1) ts += __shfl_down(ts, off, 64);
  if (lane == 0) wpart[w] = ts;
  __syncthreads();

  // ---- phase 5: publish + hierarchical last-block election ----
  if (tid == 0) {
    float s = 0.f;
#pragma unroll
    for (int i = 0; i < 8; ++i) s += wpart[i];
    meP[blk] = s;                            // plain store, no contention
    __threadfence();                         // release partials
    unsigned o1 = atomicAdd(&cnt1[(blk & 15) * 32], 1u);  // 128B-spaced lines
    int last = 0;
    if (o1 - POISON == 15u) {                // group winner (16 arrived)
      __threadfence();
      unsigned o2 = atomicAdd(cnt2, 1u);
      last = (o2 - POISON == 15u);           // global winner (16 groups)
    }
    lastBlk = last;
  }
  __syncthreads();

  // ---- finalize: last-arriving block only ----
  if (lastBlk) {
    __threadfence();                         // acquire all blocks' partials
    float e = 0.f, cs = 0.f, m = 0.f;
    if (tid < 256) { e = entP[tid]; cs = comP[tid]; m = meP[tid]; }
#pragma unroll
    for (int off = 32; off > 0; off >>= 1) {
      e  += __shfl_down(e, off, 64);
      cs += __shfl_down(cs, off, 64);
      m  += __shfl_down(m, off, 64);
    }
    if (lane == 0) { fe[w] = e; fc[w] = cs; fm[w] = m; }
    __syncthreads();                         // lastBlk is block-uniform
    if (tid == 0) {
      float E = 0.f, C = 0.f, M = 0.f;
#pragma unroll
      for (int i = 0; i < 8; ++i) { E += fe[i]; C += fc[i]; M += fm[i]; }
      double em = (double)E / 256.0;         // entro_mean_s
      double cm = (double)C / 5120.0;        // commit_loss
      double me = (double)M;                 // mean_entro
      out[5120] = (float)em;
      out[5121] = (float)me;
      out[5122] = (float)(em - me);          // entro_loss (ALPHA=1)
      out[5123] = (float)cm;
    }
  }
}

extern "C" void kernel_launch(void* const* d_in, const int* in_sizes, int n_in,
                              void* d_out, int out_size, void* d_ws, size_t ws_size,
                              hipStream_t stream) {
  const float* x = (const float*)d_in[0];
  float* out = (float*)d_out;
  char* ws = (char*)d_ws;
  float* entP = (float*)(ws);                 // 256 floats
  float* comP = (float*)(ws + 1024);          // 256 floats
  float* meP  = (float*)(ws + 2048);          // 256 floats
  unsigned* cnt1 = (unsigned*)(ws + 4096);    // 16 counters, 128B apart
  unsigned* cnt2 = (unsigned*)(ws + 4096 + 16 * 128);

  lfq_one<<<256, 512, 0, stream>>>(x, out, entP, comP, meP, cnt1, cnt2);
}

// Round 7
// 56.852 us; speedup vs baseline: 1.9992x; 1.1070x over previous
//
#include <hip/hip_runtime.h>
#include <math.h>

// LFQ: D=20 bits, K=2^20, TEMP=0.005, x:[2,128,20] fp32, 256 tokens.
// Factorized softmax over the +-1 hypercube codebook:
//   p_t(k) = prod_j sigma(2 x_tj / T)^(b_kj) * sigma(-2 x_tj / T)^(1-b_kj)
// entropy_t = sum_j H(sigma(400 x_tj)); mean_probs M = (1/256) Hi^T Lo
// (10/10 bit split); mean_entro = -sum_k M_k log(M_k + 1e-10).
//
// R7: fence-free. R3-R6 post-mortems point at agent-scope fences
// (__threadfence -> L2 writeback/invalidate per block, serialized per XCD)
// as the ~10us residual: invariant to TLP (R5) and to atomic contention
// (R6). So the last-block-finalize tail is GONE: kernel 1 ends with three
// plain float stores per block (no fence, no atomic); a trivial 1-block
// kernel 2 reduces 3x256 partials and writes the 4 scalars. Cross-kernel
// visibility is the kernel-boundary release/acquire (one CP-managed L2
// writeback total, not 256).

#define RS 264    // panel row stride in ushorts: 528B rows; frag reads and
                  // column writes both bank-phase conflict-free

typedef float f32x4 __attribute__((ext_vector_type(4)));
typedef short bf16x8 __attribute__((ext_vector_type(8)));

__device__ inline unsigned short pk_bf16(float a) {  // RNE f32->bf16
  unsigned ua = __float_as_uint(a);
  ua += 0x7FFFu + ((ua >> 16) & 1u);
  return (unsigned short)(ua >> 16);
}

__global__ __launch_bounds__(512) void lfq_main(
    const float* __restrict__ x, float* __restrict__ out,
    float* __restrict__ entP, float* __restrict__ comP,
    float* __restrict__ meP) {
  const int blk = blockIdx.x;
  const int tid = threadIdx.x;
  const int lane = tid & 63, w = tid >> 6;

  __shared__ unsigned short sP[128 * RS];   // A rows 0..63, B rows 64..127
  __shared__ float wpart[8];

  // ---- phase 1: this block's token scalars (wave 0 only, shuffle-reduced)
  if (tid < 64) {
    float h = 0.f, cterm = 0.f;
    if (tid < 20) {
      float xv = x[blk * 20 + tid];
      float z = 400.f * xv, az = fabsf(z);
      float e = __expf(-az), s = e / (1.f + e);
      h = log1pf(e) + az * s;               // stable binary entropy (nats)
      float qv = (xv > 0.f) ? 1.f : -1.f;
      out[blk * 20 + tid] = qv;             // straight-through forward value
      float dx = xv - qv;
      cterm = dx * dx;
    }
#pragma unroll
    for (int off = 32; off > 0; off >>= 1) {
      h += __shfl_down(h, off, 64);
      cterm += __shfl_down(cterm, off, 64);
    }
    if (tid == 0) { entP[blk] = h; comP[blk] = cterm; }  // plain stores
  }

  // ---- phase 2: build this side's panel column t, all in registers ----
  {
    const int side = tid >> 8;               // 0: A-panel, 1: B-panel
    const int t = tid & 255;
    const int jo = side * 10;                // x-column offset for this side
    const int hi4 = side ? (blk >> 4) : (blk & 15);  // tile's fixed 4 bits

    float p[10];
    const float2* xp = (const float2*)(x + t * 20 + jo);
#pragma unroll
    for (int k = 0; k < 5; ++k) {
      float2 v = xp[k];
      float zz0 = 400.f * v.x, zz1 = 400.f * v.y;
      float a0 = fabsf(zz0), a1 = fabsf(zz1);
      float e0 = __expf(-a0), e1 = __expf(-a1);
      float s0 = e0 / (1.f + e0), s1 = e1 / (1.f + e1);
      p[2 * k]     = (zz0 >= 0.f) ? (1.f - s0) : s0;
      p[2 * k + 1] = (zz1 >= 0.f) ? (1.f - s1) : s1;
    }
    float c = 1.f;
#pragma unroll
    for (int j = 0; j < 4; ++j)
      c *= ((hi4 >> (3 - j)) & 1) ? p[j] : (1.f - p[j]);
    float cvh[8], vl[8];
#pragma unroll
    for (int g = 0; g < 8; ++g) {
      cvh[g] = c * ((g & 4) ? p[4] : 1.f - p[4])
                 * ((g & 2) ? p[5] : 1.f - p[5])
                 * ((g & 1) ? p[6] : 1.f - p[6]);
      vl[g]  =     ((g & 4) ? p[7] : 1.f - p[7])
                 * ((g & 2) ? p[8] : 1.f - p[8])
                 * ((g & 1) ? p[9] : 1.f - p[9]);
    }
    unsigned short* panel = sP + side * 64 * RS;
#pragma unroll
    for (int r = 0; r < 64; ++r)
      panel[r * RS + t] = pk_bf16(cvh[r >> 3] * vl[r & 7]);
  }
  __syncthreads();

  // ---- phase 3: tile GEMM. wave w: rows (w&3)*16, cols (w>>2)*32 ----
  // A-frag lane: A[m=lane&15][k=q*8+j]; B-frag lane: B[k][n=lane&15];
  // both t-contiguous 16B reads. C/D layout irrelevant (pure reduction).
  const int m16 = lane & 15, q = lane >> 4;
  const unsigned short* ap = sP + ((w & 3) * 16 + m16) * RS + q * 8;
  const unsigned short* bp = sP + (64 + (w >> 2) * 32 + m16) * RS + q * 8;
  f32x4 acc0 = {0.f, 0.f, 0.f, 0.f}, acc1 = {0.f, 0.f, 0.f, 0.f};
#pragma unroll
  for (int ks = 0; ks < 8; ++ks) {
    bf16x8 af = *(const bf16x8*)(ap + ks * 32);
    bf16x8 b0 = *(const bf16x8*)(bp + ks * 32);
    bf16x8 b1 = *(const bf16x8*)(bp + 16 * RS + ks * 32);
    acc0 = __builtin_amdgcn_mfma_f32_16x16x32_bf16(af, b0, acc0, 0, 0, 0);
    acc1 = __builtin_amdgcn_mfma_f32_16x16x32_bf16(af, b1, acc1, 0, 0, 0);
  }

  // ---- phase 4: -m*log(m+1e-10) epilogue, shuffle reduce, plain store ----
  float ts = 0.f;
#pragma unroll
  for (int i = 0; i < 4; ++i) {
    float m0 = acc0[i] * (1.f / 256.f);
    ts -= m0 * __logf(m0 + 1e-10f);
    float m1 = acc1[i] * (1.f / 256.f);
    ts -= m1 * __logf(m1 + 1e-10f);
  }
#pragma unroll
  for (int off = 32; off > 0; off >>= 1) ts += __shfl_down(ts, off, 64);
  if (lane == 0) wpart[w] = ts;
  __syncthreads();
  if (tid == 0) {
    float s = 0.f;
#pragma unroll
    for (int i = 0; i < 8; ++i) s += wpart[i];
    meP[blk] = s;                            // plain store; kernel boundary
  }                                          // publishes it to kernel 2
}

__global__ __launch_bounds__(256) void lfq_finish(
    const float* __restrict__ entP, const float* __restrict__ comP,
    const float* __restrict__ meP, float* __restrict__ out) {
  const int tid = threadIdx.x;
  const int lane = tid & 63, w = tid >> 6;
  __shared__ float fe[4], fc[4], fm[4];
  float e = entP[tid], cs = comP[tid], m = meP[tid];
#pragma unroll
  for (int off = 32; off > 0; off >>= 1) {
    e  += __shfl_down(e, off, 64);
    cs += __shfl_down(cs, off, 64);
    m  += __shfl_down(m, off, 64);
  }
  if (lane == 0) { fe[w] = e; fc[w] = cs; fm[w] = m; }
  __syncthreads();
  if (tid == 0) {
    float E = 0.f, C = 0.f, M = 0.f;
#pragma unroll
    for (int i = 0; i < 4; ++i) { E += fe[i]; C += fc[i]; M += fm[i]; }
    double em = (double)E / 256.0;           // entro_mean_s
    double cm = (double)C / 5120.0;          // commit_loss
    double me = (double)M;                   // mean_entro
    out[5120] = (float)em;
    out[5121] = (float)me;
    out[5122] = (float)(em - me);            // entro_loss (ALPHA=1)
    out[5123] = (float)cm;
  }
}

extern "C" void kernel_launch(void* const* d_in, const int* in_sizes, int n_in,
                              void* d_out, int out_size, void* d_ws, size_t ws_size,
                              hipStream_t stream) {
  const float* x = (const float*)d_in[0];
  float* out = (float*)d_out;
  char* ws = (char*)d_ws;
  float* entP = (float*)(ws);                 // 256 floats
  float* comP = (float*)(ws + 1024);          // 256 floats
  float* meP  = (float*)(ws + 2048);          // 256 floats

  lfq_main<<<256, 512, 0, stream>>>(x, out, entP, comP, meP);
  lfq_finish<<<1, 256, 0, stream>>>(entP, comP, meP, out);
}